// Round 14
// baseline (300.236 us; speedup 1.0000x reference)
//
#include <hip/hip_runtime.h>
#include <hip/hip_bf16.h>
#include <math.h>

#define IC 512
#define OC 512
#define STYLE 512
#define BB 8
#define H_ 64
#define W_ 64
#define HW 4096
#define HP 66          // padded rows (zero row above and below)
#define KC 32          // channel chunk per MFMA K-step
#define NCHUNK 16
#define USTRIDE 1056   // bytes per u-granule plane in conv LDS: 66 cols * 16B
#define ROWSTRIDE 4224 // 4 * USTRIDE
#define BUFSZ (6 * ROWSTRIDE)   // 25344 B per x buffer

typedef __attribute__((ext_vector_type(8))) __bf16 bf16x8;
typedef __attribute__((ext_vector_type(4))) float floatx4;
typedef __attribute__((ext_vector_type(16))) float floatx16;

static __device__ __forceinline__ unsigned short f2bf(float f) {
    unsigned u = __builtin_bit_cast(unsigned, f);
    unsigned r = u + 0x7FFFu + ((u >> 16) & 1u);   // RNE
    return (unsigned short)(r >> 16);
}

// async global->LDS DMA, 16B per lane. dst is wave-uniform base; HW writes lane i at dst + i*16.
static __device__ __forceinline__ void gload_lds16(const unsigned short* g, unsigned char* l) {
    __builtin_amdgcn_global_load_lds((const __attribute__((address_space(1))) unsigned int*)g,
                                     (__attribute__((address_space(3))) unsigned int*)l,
                                     16, 0, 0);
}

// ---------------- K1: s[b,i] = MOD_SCALE * style[b,:]·(mod_weight + fcB@fcA^T)[i,:] + biases
// grid (32, 8), block 512: i = bx*16 + (tid>>5); jg = tid&31 handles 16 j's.
__global__ __launch_bounds__(512) void k_style(const float* __restrict__ style,
                        const float* __restrict__ mod_weight,
                        const float* __restrict__ mod_bias, const float* __restrict__ fc_lora_A,
                        const float* __restrict__ fc_lora_B, const float* __restrict__ fc_lora_bias,
                        float* __restrict__ s_out) {
    int b = blockIdx.y;
    int i = blockIdx.x * 16 + (threadIdx.x >> 5);
    int jg = threadIdx.x & 31;
    float4 fb = *(const float4*)&fc_lora_B[i * 4];
    const float* st = style + b * STYLE;
    const float* mw = mod_weight + (size_t)i * STYLE;
    float acc = 0.f;
    for (int j = jg * 16; j < jg * 16 + 16; ++j) {
        float4 fa = *(const float4*)&fc_lora_A[j * 4];
        float w = mw[j] + fb.x * fa.x + fb.y * fa.y + fb.z * fa.z + fb.w * fa.w;
        acc += st[j] * w;
    }
    #pragma unroll
    for (int off = 16; off; off >>= 1) acc += __shfl_down(acc, off, 32);
    if (jg == 0) {
        float mod_scale = 1.0f / sqrtf((float)STYLE);
        s_out[b * IC + i] = mod_scale * acc + mod_bias[i] + fc_lora_bias[i];
    }
}

// ---------------- K2 (merged): block-specialized prep dispatch.
// blocks [0,512):   weight+scale path (block = one o): w5 -> swizzled wb + block-reduced scale[b][o]
// blocks [512,2624): stage_x path: NCHW fp32 -> xm[b][hp][ci][u][w][8ch] bf16, modulated by s
// wb layout (32x32x16 A-frags): [t(9)][ot(8)][mt(2)*2+kh(2)][ci(16)][lane(64)][8]
//   A mapping: oc row = lane&31 (o&31), k = (lane>>5)*8 + e with channel i = ci*32+kh*16+(lane>>5)*8+e
__global__ __launch_bounds__(512) void k_prep(const float* __restrict__ weight,
                         const float* __restrict__ llB,
                         const float* __restrict__ llBinst, const float* __restrict__ llA,
                         const float* __restrict__ s,
                         unsigned short* __restrict__ wb, float* __restrict__ scale,
                         const float* __restrict__ x, unsigned short* __restrict__ xm) {
    __shared__ float tile[128 * 65];               // stage path; weight path aliases first 64 floats
    const int bid = blockIdx.x;
    if (bid < 512) {
        // ================= weight + scale path =================
        float (*red)[8] = (float(*)[8])tile;       // [wave][b]
        int o = bid;                               // 0..511
        int i = threadIdx.x;                       // 0..511
        int wv = i >> 6, lane64 = i & 63;
        float4 vB = *(const float4*)&llB[o * 4];
        float4 vA = *(const float4*)&llA[i * 4];
        const float* wrow = weight + (size_t)(o * IC + i) * 9;
        int lane = ((i >> 3) & 1) * 32 + (o & 31); // (lane>>5) = k-octet select, lane&31 = oc row
        size_t wbase = ((size_t)(((o >> 6) * 4 + ((o >> 5) & 1) * 2 + ((i >> 4) & 1)) * 16
                                 + (i >> 5)) * 64 + lane) * 8 + (i & 7);
        float w2 = 0.f;
        #pragma unroll
        for (int k = 0; k < 9; ++k) {
            float wadd = 0.f;
            #pragma unroll
            for (int bb = 0; bb < 4; ++bb) {
                float bm = vB.x * llBinst[(bb * 4 + 0) * 9 + k] + vB.y * llBinst[(bb * 4 + 1) * 9 + k]
                         + vB.z * llBinst[(bb * 4 + 2) * 9 + k] + vB.w * llBinst[(bb * 4 + 3) * 9 + k];
                bm = fmaxf(bm, 0.f);
                float a = (bb == 0) ? vA.x : (bb == 1) ? vA.y : (bb == 2) ? vA.z : vA.w;
                wadd += a * bm;
            }
            wadd = fmaxf(wadd, 0.f);
            float w5 = wrow[k] + wadd;             // LORA_ALPHA_CONV = 1
            wb[(size_t)k * 262144 + wbase] = f2bf(w5);
            w2 += w5 * w5;
        }
        // per-b partials: w2 * s[b,i]^2, wave-reduced then cross-wave via tiny LDS
        float partial[8];
        #pragma unroll
        for (int b = 0; b < 8; ++b) {
            float sv = s[b * IC + i];
            partial[b] = w2 * sv * sv;
        }
        #pragma unroll
        for (int off = 32; off; off >>= 1)
            #pragma unroll
            for (int b = 0; b < 8; ++b)
                partial[b] += __shfl_down(partial[b], off, 64);
        if (lane64 == 0)
            #pragma unroll
            for (int b = 0; b < 8; ++b)
                red[wv][b] = partial[b];
        __syncthreads();
        if (i < 8) {
            float acc = 0.f;
            #pragma unroll
            for (int w = 0; w < 8; ++w) acc += red[w][i];
            float cs = 1.0f / sqrtf((float)(IC * 9));
            scale[i * OC + o] = cs * rsqrtf(cs * cs * acc + 1e-8f);
        }
    } else {
        // ================= stage_x path (512 threads) =================
        int sb_ = bid - 512;                       // 0..2111 = cc + 4*(hp + 66*b)
        int cc = sb_ & 3;                          // 0..3 (128-channel chunk)
        int t2 = sb_ >> 2;                         // 0..527
        int hp = t2 % 66;                          // 0..65
        int b  = t2 / 66;                          // 0..7
        int c0 = cc * 128;
        int tid = threadIdx.x;                     // 0..511
        if (hp == 0 || hp == HP - 1) {
            unsigned short* dst = xm + (size_t)(b * HP + hp) * 32768 + cc * 8192;
            uint4 z = make_uint4(0, 0, 0, 0);
            #pragma unroll
            for (int p = 0; p < 2; ++p)
                *(uint4*)(dst + (size_t)(p * 512 + tid) * 8) = z;
            return;
        }
        int h = hp - 1;
        const float* xin = x + (((size_t)b * IC + c0) * H_ + h) * W_;
        #pragma unroll
        for (int p = 0; p < 16; ++p) {
            int idx = p * 512 + tid;
            int c = idx >> 6, w = idx & 63;
            tile[c * 65 + w] = xin[(size_t)c * HW + w];
        }
        __syncthreads();
        const float* sb2 = s + b * IC + c0;
        #pragma unroll
        for (int p = 0; p < 2; ++p) {
            int idx = p * 512 + tid;               // 0..1023
            int cil = idx >> 8;                    // local ci 0..3
            int u   = (idx >> 6) & 3;
            int w   = idx & 63;
            int cb  = cil * 32 + u * 8;
            unsigned int packed[4];
            #pragma unroll
            for (int k = 0; k < 4; ++k) {
                unsigned lo = f2bf(tile[(cb + 2 * k) * 65 + w] * sb2[cb + 2 * k]);
                unsigned hi = f2bf(tile[(cb + 2 * k + 1) * 65 + w] * sb2[cb + 2 * k + 1]);
                packed[k] = lo | (hi << 16);
            }
            size_t g = (((size_t)(b * HP + hp) * 16 + (cc * 4 + cil)) * 4 + u) * 64 + w;
            *(uint4*)(xm + g * 8) = make_uint4(packed[0], packed[1], packed[2], packed[3]);
        }
    }
}

// ---------------- K5: conv. R9 geometry + per-tap phase alignment (R10 winner), MFMA shape
// switched 16x16x32 -> 32x32x16 (2382 vs 2075 TF: MFMA floor/SIMD 179K -> 149K cyc, half the
// MFMA instructions). Per tap: 4 af + 4 bv loads (same bytes) -> 8 MFMAs (2mt x 2nt x 2 ch).
// B mapping: col w = nt*32 + (lane&31), k = (lane>>5)*8+e -> granule u = ch*2+(lane>>5).
// C/D (m74/m101): col = lane&31, row = (reg&3) + 8*(reg>>2) + 4*(lane>>5).
#define STAGE3(CN, BSEL)                                                                         \
    _Pragma("unroll")                                                                            \
    for (int j = 0; j < 3; ++j) {                                                                \
        const int g_ = wave * 3 + j;                                                             \
        const int row_ = g_ >> 2, u_ = g_ & 3;                                                   \
        gload_lds16(xmb + ((((size_t)(h0 + row_) * 16 + (CN)) * 4 + u_) * 64 + lane) * 8,        \
                    xs + (size_t)(BSEL) * BUFSZ + (size_t)row_ * ROWSTRIDE + u_ * USTRIDE + 16); \
    }

#define STAGE1(CN, BSEL, J)                                                                      \
    {   const int g_ = wave * 3 + (J);                                                           \
        const int row_ = g_ >> 2, u_ = g_ & 3;                                                   \
        gload_lds16(xmb + ((((size_t)(h0 + row_) * 16 + (CN)) * 4 + u_) * 64 + lane) * 8,        \
                    xs + (size_t)(BSEL) * BUFSZ + (size_t)row_ * ROWSTRIDE + u_ * USTRIDE + 16); \
    }

__global__ __launch_bounds__(512, 4) void k_conv(const unsigned short* __restrict__ wb,
                                                 const unsigned short* __restrict__ xm,
                                                 const float* __restrict__ scale,
                                                 float* __restrict__ out) {
    __shared__ unsigned char xs[2 * BUFSZ];        // 50688 B; epilogue reuses (34816 B)
    const int tid = threadIdx.x;                   // 0..511
    const int wave = tid >> 6, lane = tid & 63;    // 8 waves
    const int l16 = lane & 15;
    const int l31 = lane & 31, lh = lane >> 5;
    const int ow = wave >> 2;           // 0..1 oc-half
    const int wr = wave & 3;            // 0..3 output row within tile
    const int wgid = blockIdx.x;        // 0..511
    const int ot2 = wgid & 3;           // ot-pair, pinned per XCD (wgid%8 -> XCD; ot2 = xcd&3)
    const int rr = wgid >> 2;           // 0..127
    const int ht = rr & 15;             // 0..15
    const int b  = rr >> 4;             // 0..7
    const int ot = ot2 * 2 + ow;        // 0..7
    const int om = ot * 64;
    const int h0 = ht * 4;

    // zero border col-granules (cols 0 and 65, all 6 rows, all u, BOTH buffers): 96 x 16B
    if (tid < 96) {
        int bsel = tid >= 48;
        int t48 = tid - bsel * 48;
        int row = t48 >> 3;
        int rem = t48 & 7;
        int u = rem >> 1;
        int side = rem & 1;
        uint4 z = make_uint4(0, 0, 0, 0);
        *(uint4*)(xs + bsel * BUFSZ + row * ROWSTRIDE + u * USTRIDE + side * 65 * 16) = z;
    }

    floatx16 acc[2][2];
    #pragma unroll
    for (int mt = 0; mt < 2; ++mt)
        #pragma unroll
        for (int nt = 0; nt < 2; ++nt)
            acc[mt][nt] = (floatx16)(0.f);

    // x staging: 24 granule-planes (6 rows x 4 u) split 3 per wave; DMA writes lanes at dst+lane*16
    const unsigned short* xmb = xm + (size_t)b * HP * 32768;
    // weights: swizzled so per-wave load is base + lane*16B (coalesced)
    const unsigned short* wlb = wb + (size_t)ot * 32768 + (size_t)lane * 8;

    // prologue: DMA chunk 0 into buffer 0
    STAGE3(0, 0)

    int cur = 0;
    for (int ci = 0; ci < NCHUNK; ++ci) {
        __syncthreads();                // chunk boundary: drains DMA for buf[cur] + visibility
        const unsigned char* buf = xs + (size_t)cur * BUFSZ;
        const unsigned short* wlc = wlb + (size_t)ci * 512;
        #pragma unroll
        for (int kr = 0; kr < 3; ++kr) {
            #pragma unroll
            for (int dw = 0; dw < 3; ++dw) {
                const int t = kr * 3 + dw;
                // spread next-chunk stage DMAs across taps 0..2 (one per tap per wave)
                if (t < 3 && ci + 1 < NCHUNK) STAGE1(ci + 1, cur ^ 1, t)
                bf16x8 af[2][2], bv[2][2];
                #pragma unroll
                for (int mt = 0; mt < 2; ++mt)
                    #pragma unroll
                    for (int ch = 0; ch < 2; ++ch)
                        af[mt][ch] = *(const bf16x8*)(wlc + (size_t)t * 262144 + (mt * 2 + ch) * 8192);
                #pragma unroll
                for (int nt = 0; nt < 2; ++nt)
                    #pragma unroll
                    for (int ch = 0; ch < 2; ++ch)
                        bv[nt][ch] = *(const bf16x8*)(buf + (size_t)(wr + kr) * ROWSTRIDE
                                                      + (ch * 2 + lh) * USTRIDE
                                                      + (nt * 32 + l31 + dw) * 16);
                __builtin_amdgcn_s_setprio(1);
                #pragma unroll
                for (int mt = 0; mt < 2; ++mt)
                    #pragma unroll
                    for (int nt = 0; nt < 2; ++nt) {
                        acc[mt][nt] = __builtin_amdgcn_mfma_f32_32x32x16_bf16(af[mt][0], bv[nt][0], acc[mt][nt], 0, 0, 0);
                        acc[mt][nt] = __builtin_amdgcn_mfma_f32_32x32x16_bf16(af[mt][1], bv[nt][1], acc[mt][nt], 0, 0, 0);
                    }
                __builtin_amdgcn_s_setprio(0);
                __builtin_amdgcn_s_barrier();   // per-tap alignment (uniform; no data dep)
            }
        }
        cur ^= 1;
    }

    // ---- epilogue: scale, then stage through LDS for fully-coalesced float4 stores
    // C/D: col = lane&31, row(reg) = (reg&3) + 8*(reg>>2) + 4*(lane>>5). Iterate (mt, s):
    // regs r = s*8+q' cover tile rows s*16 + [(q'&3) + 8*(q'>>2) + 4*lh] = s*16 + 0..15.
    __syncthreads();                    // all waves done with both x buffers
    float* ebuf = (float*)xs + wave * 1088;        // 16 oc-rows x 68 floats per wave (34816 B total)
    const int h = h0 + wr;
    const float* scb = scale + b * OC + om;
    #pragma unroll
    for (int mt = 0; mt < 2; ++mt) {
        #pragma unroll
        for (int s = 0; s < 2; ++s) {
            const int rbase = mt * 32 + s * 16;
            float4 sc0 = *(const float4*)&scb[rbase + 4 * lh];      // rows 0..3 + 4*lh
            float4 sc1 = *(const float4*)&scb[rbase + 8 + 4 * lh];  // rows 8..11 + 4*lh
            const float* s0 = (const float*)&sc0;
            const float* s1 = (const float*)&sc1;
            #pragma unroll
            for (int nt = 0; nt < 2; ++nt)
                #pragma unroll
                for (int q = 0; q < 8; ++q) {
                    const int rl = (q & 3) + 8 * (q >> 2) + 4 * lh;  // 0..15
                    const float sv = (q < 4) ? s0[q & 3] : s1[q & 3];
                    ebuf[rl * 68 + nt * 32 + l31] = acc[mt][nt][s * 8 + q] * sv;
                }
            __syncthreads();            // uniform; guarantees write->read ordering
            #pragma unroll
            for (int q = 0; q < 4; ++q) {
                int r0 = q * 4 + (lane >> 4);
                int c0 = (lane & 15) * 4;
                float4 v = *(float4*)&ebuf[r0 * 68 + c0];
                *(float4*)&out[((size_t)(b * OC + om + rbase + r0)) * HW + h * W_ + c0] = v;
            }
            __syncthreads();            // reads done before next iteration's writes
        }
    }
}

extern "C" void kernel_launch(void* const* d_in, const int* in_sizes, int n_in,
                              void* d_out, int out_size, void* d_ws, size_t ws_size,
                              hipStream_t stream) {
    const float* input   = (const float*)d_in[0];
    const float* style   = (const float*)d_in[1];
    const float* weight  = (const float*)d_in[2];
    const float* llB     = (const float*)d_in[3];
    const float* llBinst = (const float*)d_in[4];
    const float* llA     = (const float*)d_in[5];
    const float* mod_w   = (const float*)d_in[6];
    const float* mod_b   = (const float*)d_in[7];
    const float* fcA     = (const float*)d_in[8];
    const float* fcB     = (const float*)d_in[9];
    const float* fcBias  = (const float*)d_in[10];
    float* out = (float*)d_out;

    char* ws = (char*)d_ws;
    float* s_ws            = (float*)(ws + 0);                  // 16 KB
    float* scale_ws        = (float*)(ws + 16384);              // 16 KB
    unsigned short* wb_ws  = (unsigned short*)(ws + 32768);                    // 4.72 MB
    unsigned short* xm_ws  = (unsigned short*)(ws + 32768 + 4718592);          // 34.6 MB

    k_style<<<dim3(32, 8), 512, 0, stream>>>(style, mod_w, mod_b, fcA, fcB, fcBias, s_ws);
    k_prep<<<2624, 512, 0, stream>>>(weight, llB, llBinst, llA, s_ws, wb_ws, scale_ws,
                                     input, xm_ws);
    k_conv<<<512, 512, 0, stream>>>(wb_ws, xm_ws, scale_ws, out);
}